// Round 2
// baseline (133.265 us; speedup 1.0000x reference)
//
#include <hip/hip_runtime.h>
#include <hip/hip_bf16.h>

// QLoRA fwd: y = x @ (NF4dequant(codes,absmax) + adapter)^T
// x [1048576, 64] f32; combined W [64,64]; y [1048576, 64] f32.
// Memory-bound: 268MB read + 268MB write -> ~85us floor @6.3TB/s copy ceiling.
// R2: explicit 2-deep load pipeline (issue next strip's loads before current
// strip's stores -> counted vmcnt, stores drain in background), fully-resident
// grid (1024 blk x 4 waves = 16 waves/CU, launch_bounds(256,4)), non-temporal
// loads/stores (zero reuse, don't pollute L2/L3), v_cvt_pk_bf16_f32 via
// __float22bfloat162_rn.

#define IN_F 64
#define OUT_F 64
#define N_TOKENS 1048576

typedef __attribute__((ext_vector_type(8))) short bf16x8;   // 8 bf16 (4 VGPRs)
typedef __attribute__((ext_vector_type(4))) float f32x4;    // 4 f32

__device__ __constant__ float NF4_CODE_D[16] = {
    -1.0f, -0.6961928009986877f, -0.5250730514526367f, -0.39491748809814453f,
    -0.28444138169288635f, -0.18477343022823334f, -0.09105003625154495f, 0.0f,
    0.07958029955625534f, 0.16093020141124725f, 0.24611230194568634f,
    0.33791524171829224f, 0.44070982933044434f, 0.5626170039176941f,
    0.7229568362236023f, 1.0f};

__device__ __forceinline__ unsigned short f32_to_bf16_rne(float f) {
    union { float f; unsigned int u; } v; v.f = f;
    unsigned int b = v.u + 0x7fffu + ((v.u >> 16) & 1u);
    return (unsigned short)(b >> 16);
}

// pack two f32 -> one dword of 2 bf16 (compiler emits v_cvt_pk_bf16_f32)
__device__ __forceinline__ unsigned int cvt2(float lo, float hi) {
    __hip_bfloat162 h = __float22bfloat162_rn(make_float2(lo, hi));
    union { __hip_bfloat162 h; unsigned int u; } c; c.h = h;
    return c.u;
}

union BF8 { bf16x8 v; unsigned int u[4]; };

// --- Kernel 1: combined weight dequant+adapter-add, 4096 elements ---
// BLOCKSIZE==IN_F==64 => NF4 block index b == output row o.
__global__ void dequant_weight_kernel(const int* __restrict__ codes,
                                      const float* __restrict__ absmax,
                                      const float* __restrict__ adapter,
                                      unsigned short* __restrict__ wbf) {
    int e = blockIdx.x * blockDim.x + threadIdx.x;
    if (e < OUT_F * IN_F) {
        int o = e >> 6;
        float w = NF4_CODE_D[codes[e]] * absmax[o] + adapter[e];
        wbf[e] = f32_to_bf16_rne(w);
    }
}

// --- Kernel 2: tall-skinny GEMM via MFMA 16x16x32 bf16, 2-deep pipeline ---
// Per wave per strip of 16 tokens:
//   A-frag (W, regs): lane l holds W[j*16+(l&15)][s*32+(l>>4)*8 + 0..7]
//   B-frag (x):       lane l holds x[t0+(l&15)][s*32+(l>>4)*8 + 0..7]
//   D[o][t]: lane l -> token t0+(l&15), outs j*16+(l>>4)*4+r
__global__ __launch_bounds__(256, 4) void qlora_gemm_kernel(
    const float* __restrict__ x,
    const unsigned short* __restrict__ wbf,
    float* __restrict__ y) {

    const int lane  = threadIdx.x & 63;
    const int wave  = blockIdx.x * 4 + (threadIdx.x >> 6);
    const int row16 = lane & 15;
    const int kgrp  = lane >> 4;

    // Weight fragments, loaded once (8KB table, L2-resident).
    bf16x8 afrag[4][2];
#pragma unroll
    for (int j = 0; j < 4; ++j)
#pragma unroll
        for (int s = 0; s < 2; ++s)
            afrag[j][s] = *(const bf16x8*)(wbf + (j * 16 + row16) * 64 + s * 32 + kgrp * 8);

    const int STRIPS = 16;                       // 4096 waves x 16 strips = 65536
    const long t0 = (long)wave * (STRIPS * 16);  // contiguous 64KB chunk per wave
    const float* xp = x + (t0 + row16) * 64 + kgrp * 8;
    float*       yp = y + (t0 + row16) * 64 + kgrp * 4;
    // strip-to-strip stride: 16 tokens * 64 floats = 1024

    // prologue: strip 0 loads
    f32x4 a0 = __builtin_nontemporal_load((const f32x4*)(xp));
    f32x4 a1 = __builtin_nontemporal_load((const f32x4*)(xp + 4));
    f32x4 a2 = __builtin_nontemporal_load((const f32x4*)(xp + 32));
    f32x4 a3 = __builtin_nontemporal_load((const f32x4*)(xp + 36));

    for (int i = 0; i < STRIPS; ++i) {
        // issue next strip's loads FIRST (oldest-vs-stores => counted vmcnt)
        f32x4 n0, n1, n2, n3;
        if (i + 1 < STRIPS) {
            const float* xn = xp + (i + 1) * 1024;
            n0 = __builtin_nontemporal_load((const f32x4*)(xn));
            n1 = __builtin_nontemporal_load((const f32x4*)(xn + 4));
            n2 = __builtin_nontemporal_load((const f32x4*)(xn + 32));
            n3 = __builtin_nontemporal_load((const f32x4*)(xn + 36));
        }

        // convert current strip to bf16 B-fragments (v_cvt_pk_bf16_f32)
        BF8 b0, b1;
        b0.u[0] = cvt2(a0[0], a0[1]); b0.u[1] = cvt2(a0[2], a0[3]);
        b0.u[2] = cvt2(a1[0], a1[1]); b0.u[3] = cvt2(a1[2], a1[3]);
        b1.u[0] = cvt2(a2[0], a2[1]); b1.u[1] = cvt2(a2[2], a2[3]);
        b1.u[2] = cvt2(a3[0], a3[1]); b1.u[3] = cvt2(a3[2], a3[3]);

        float* ypi = yp + i * 1024;
#pragma unroll
        for (int j = 0; j < 4; ++j) {
            f32x4 c = {0.f, 0.f, 0.f, 0.f};
            c = __builtin_amdgcn_mfma_f32_16x16x32_bf16(afrag[j][0], b0.v, c, 0, 0, 0);
            c = __builtin_amdgcn_mfma_f32_16x16x32_bf16(afrag[j][1], b1.v, c, 0, 0, 0);
            __builtin_nontemporal_store(c, (f32x4*)(ypi + j * 16));
        }

        a0 = n0; a1 = n1; a2 = n2; a3 = n3;  // rotate (named regs, static idx)
    }
}

extern "C" void kernel_launch(void* const* d_in, const int* in_sizes, int n_in,
                              void* d_out, int out_size, void* d_ws, size_t ws_size,
                              hipStream_t stream) {
    const float* x       = (const float*)d_in[0];
    const int*   codes   = (const int*)d_in[1];
    const float* absmax  = (const float*)d_in[2];
    const float* adapter = (const float*)d_in[3];
    float* y = (float*)d_out;
    unsigned short* wbf = (unsigned short*)d_ws;  // 64*64 bf16 = 8KB scratch

    dequant_weight_kernel<<<16, 256, 0, stream>>>(codes, absmax, adapter, wbf);

    // 1024 blocks x 256 thr = 4096 waves, fully resident at 4 blocks/CU.
    qlora_gemm_kernel<<<1024, 256, 0, stream>>>(x, wbf, y);
}